// Round 16
// baseline (551.063 us; speedup 1.0000x reference)
//
#include <hip/hip_runtime.h>
#include <hip/hip_bf16.h>
#include <hip/hip_fp16.h>
#include <math.h>

// Problem constants
#define B 32
#define N 128
#define BT (B*N)          // 4096
#define WD 100
#define UD 25
#define D 125             // LSTM hidden per direction
#define G4 (4*D)          // 500 gates
#define H2 (2*D)          // 250
#define HID 100
#define L 50

// Fast, overflow-safe activations on v_exp_f32
__device__ __forceinline__ float fast_tanh(float x) {
    float e = __expf(2.0f * x);
    return 1.0f - 2.0f / (e + 1.0f);
}
__device__ __forceinline__ float fast_sigmoid(float x) {
    return 1.0f / (1.0f + __expf(-x));
}
__device__ __forceinline__ float bcast_lane(float v, int k) {
    return __builtin_bit_cast(float, __builtin_amdgcn_readlane(__builtin_bit_cast(int, v), k));
}
__device__ __forceinline__ unsigned bcast_lane_u(unsigned v, int k) {
    return (unsigned)__builtin_amdgcn_readlane((int)v, k);
}

// pack two f32 into one u32 of 2 f16 (lo, hi), RTNE
__device__ __forceinline__ unsigned pack_f16x2(float lo, float hi) {
    __half hl = __float2half_rn(lo), hh = __float2half_rn(hi);
    unsigned a = (unsigned)__builtin_bit_cast(unsigned short, hl);
    unsigned b = (unsigned)__builtin_bit_cast(unsigned short, hh);
    return a | (b << 16);
}

typedef _Float16 h2_t __attribute__((ext_vector_type(2)));
// acc += w.lo*h.lo + w.hi*h.hi   (fp32 accumulate)
__device__ __forceinline__ float dot2acc(unsigned wu, unsigned hu, float acc) {
#if __has_builtin(__builtin_amdgcn_fdot2)
    return __builtin_amdgcn_fdot2(__builtin_bit_cast(h2_t, wu),
                                  __builtin_bit_cast(h2_t, hu), acc, false);
#else
    h2_t wv = __builtin_bit_cast(h2_t, wu);
    h2_t hv = __builtin_bit_cast(h2_t, hu);
    acc = fmaf((float)wv[0], (float)hv[0], acc);
    acc = fmaf((float)wv[1], (float)hv[1], acc);
    return acc;
#endif
}

// ---------------------------------------------------------------------------
// K_setup: ONE launch for {8 weight transposes, embedding gather, fused
// biases, Whh f16-pair packing}. Grid: [0,TR) transpose tiles,
// [TR,TR+2048) embed, then 9 bias blocks, then 512 pack blocks.
// ---------------------------------------------------------------------------
struct TJob { const float* src; float* dst; int R, C, ldo, coff, tile0, tiles_x; };
struct TArgs { TJob j[8]; };

__global__ __launch_bounds__(256)
void setup_fused(TArgs a, int n_tr,
                 const int* __restrict__ wids, const int* __restrict__ uids,
                 const float* __restrict__ wl, const float* __restrict__ tl,
                 float* __restrict__ words,
                 const float* __restrict__ l0f_b, const float* __restrict__ l0b_b,
                 const float* __restrict__ l1f_b, const float* __restrict__ l1b_b,
                 const float* __restrict__ eh_b, const float* __restrict__ em_b,
                 const float* __restrict__ lm_b,
                 float* __restrict__ b_l0, float* __restrict__ b_l1,
                 float* __restrict__ b_s3,
                 const float* __restrict__ s0, const float* __restrict__ s1,
                 const float* __restrict__ s2, const float* __restrict__ s3w,
                 unsigned* __restrict__ d0, unsigned* __restrict__ d1,
                 unsigned* __restrict__ d2, unsigned* __restrict__ d3) {
    __shared__ float tile[32][33];
    int bid = blockIdx.x;
    int tid = threadIdx.x;
    if (bid < n_tr) {                    // ---- transpose tiles ----
        int ji = 0;
        #pragma unroll
        for (int i = 1; i < 8; i++) if (bid >= a.j[i].tile0) ji = i;
        TJob jb = a.j[ji];
        int t = bid - jb.tile0;
        int tx = t % jb.tiles_x, ty = t / jb.tiles_x;
        int txx = tid & 31, tyy = tid >> 5;      // 32 x 8
        int k0 = tx*32, n0 = ty*32;
        #pragma unroll
        for (int dy = 0; dy < 32; dy += 8) {
            int n = n0 + tyy + dy, k = k0 + txx;
            if (n < jb.R && k < jb.C)
                tile[tyy+dy][txx] = jb.src[(size_t)n*jb.C + k];
        }
        __syncthreads();
        #pragma unroll
        for (int dy = 0; dy < 32; dy += 8) {
            int k = k0 + tyy + dy, n = n0 + txx;
            if (k < jb.C && n < jb.R)
                jb.dst[(size_t)k*jb.ldo + jb.coff + n] = tile[txx][tyy+dy];
        }
        return;
    }
    bid -= n_tr;
    if (bid < 2048) {                    // ---- embed: 2 bt per block ----
        int bt = bid*2 + (tid >> 7);
        int t = tid & 127;
        int wid = wids[bt], uid = uids[bt];
        if (t < WD)       words[bt*D + t] = wl[(size_t)wid*WD + t];
        else if (t < D)   words[bt*D + t] = tl[(size_t)uid*UD + (t - WD)];
        return;
    }
    bid -= 2048;
    if (bid < 9) {                       // ---- fused biases ----
        int t = bid*256 + tid;
        if (t < 500)        b_l0[t] = l0f_b[t];
        else if (t < 1000)  b_l0[t] = l0b_b[t-500];
        else if (t < 1500)  b_l1[t-1000] = l1f_b[t-1000];
        else if (t < 2000)  b_l1[t-1000] = l1b_b[t-1500];
        else if (t < 2100)  b_s3[t-2000] = eh_b[t-2000];
        else if (t < 2200)  b_s3[t-2000] = em_b[t-2100];
        else if (t < 2300)  b_s3[t-2000] = lm_b[t-2200];
        return;
    }
    bid -= 9;                            // ---- Whh f16-pair pack (512 blocks) ----
    // WhH[pk][g] (u32, [64][512]) = pack_f16x2(Whh[g][2pk], Whh[g][2pk+1])
    // Whh is [500][125] row-major; zero-fill k>=125, g>=500.
    int e = bid*256 + tid;               // exactly 4*64*512 = 131072
    int m = e >> 15;                     // buffer 0..3
    int r = e & 32767;
    int pk = r >> 9;                     // 0..63
    int g  = r & 511;                    // 0..511
    const float* s = (m == 0) ? s0 : (m == 1) ? s1 : (m == 2) ? s2 : s3w;
    unsigned* dd   = (m == 0) ? d0 : (m == 1) ? d1 : (m == 2) ? d2 : d3;
    float v0 = 0.0f, v1 = 0.0f;
    if (g < 500) {
        int k0 = pk << 1;
        if (k0 < 125)     v0 = s[(size_t)g*125 + k0];
        if (k0 + 1 < 125) v1 = s[(size_t)g*125 + k0 + 1];
    }
    dd[(pk << 9) + g] = pack_f16x2(v0, v1);
}

// ---------------------------------------------------------------------------
// K2: projection GEMM, transposed weights, CPT columns per thread,
//     software-pipelined WT loads (prefetch next k-group).
// ---------------------------------------------------------------------------
#define MT 16
template<int CPT, int BD>
__device__ __forceinline__
void proj_body(const float* __restrict__ x, const float* __restrict__ WT,
               const float* __restrict__ bias, float* __restrict__ out,
               int Ncols, int K, int ldx, const int* __restrict__ gather_idx,
               int blk, float* xs) {
    int m0 = blk * MT;
    for (int e = threadIdx.x; e < MT * K; e += BD) {
        int r = e / K, k = e - r * K;
        int m = m0 + r;
        int row = m;
        if (gather_idx) {
            int bb = m >> 7, np = m & 127;
            row = (bb << 7) + (np == 0 ? 0 : gather_idx[m]);
        }
        xs[k*17 + r] = x[(size_t)row*ldx + k];
    }
    __syncthreads();
    int n0 = threadIdx.x;
    int lane = threadIdx.x & 63;
    float acc[CPT][MT];
    int ncl[CPT];
    #pragma unroll
    for (int j = 0; j < CPT; j++) {
        int n = n0 + j*BD;
        ncl[j] = (n < Ncols) ? n : (Ncols - 1);
        #pragma unroll
        for (int r = 0; r < MT; r++) acc[j][r] = 0.0f;
    }
    float wkc[4][CPT];
    #pragma unroll
    for (int q = 0; q < 4; q++)
        #pragma unroll
        for (int j = 0; j < CPT; j++)
            wkc[q][j] = WT[(size_t)q*Ncols + ncl[j]];
    int k0 = 0;
    for (; k0 + 8 <= K; k0 += 4) {
        float xv = xs[(k0 + (lane >> 4))*17 + (lane & 15)];
        float wkn[4][CPT];
        #pragma unroll
        for (int q = 0; q < 4; q++)
            #pragma unroll
            for (int j = 0; j < CPT; j++)
                wkn[q][j] = WT[(size_t)(k0 + 4 + q)*Ncols + ncl[j]];
        #pragma unroll
        for (int q = 0; q < 4; q++) {
            #pragma unroll
            for (int r = 0; r < 16; r++) {
                float hv = bcast_lane(xv, q*16 + r);
                #pragma unroll
                for (int j = 0; j < CPT; j++)
                    acc[j][r] = fmaf(wkc[q][j], hv, acc[j][r]);
            }
        }
        #pragma unroll
        for (int q = 0; q < 4; q++)
            #pragma unroll
            for (int j = 0; j < CPT; j++)
                wkc[q][j] = wkn[q][j];
    }
    { // last full group
        float xv = xs[(k0 + (lane >> 4))*17 + (lane & 15)];
        #pragma unroll
        for (int q = 0; q < 4; q++) {
            #pragma unroll
            for (int r = 0; r < 16; r++) {
                float hv = bcast_lane(xv, q*16 + r);
                #pragma unroll
                for (int j = 0; j < CPT; j++)
                    acc[j][r] = fmaf(wkc[q][j], hv, acc[j][r]);
            }
        }
        k0 += 4;
    }
    for (; k0 < K; k0++) {
        float xv = xs[k0*17 + (lane & 15)];
        float wk[CPT];
        #pragma unroll
        for (int j = 0; j < CPT; j++) wk[j] = WT[(size_t)k0*Ncols + ncl[j]];
        #pragma unroll
        for (int r = 0; r < 16; r++) {
            float hv = bcast_lane(xv, r);
            #pragma unroll
            for (int j = 0; j < CPT; j++)
                acc[j][r] = fmaf(wk[j], hv, acc[j][r]);
        }
    }
    #pragma unroll
    for (int j = 0; j < CPT; j++) {
        int n = n0 + j*BD;
        if (n < Ncols) {
            float bb = bias[n];
            #pragma unroll
            for (int r = 0; r < MT; r++) out[(size_t)(m0 + r)*Ncols + n] = acc[j][r] + bb;
        }
    }
}

__global__ __launch_bounds__(512)
void proj_t(const float* __restrict__ x, const float* __restrict__ WT,
            const float* __restrict__ bias, float* __restrict__ out,
            int Ncols, int K, int ldx) {
    __shared__ float xs[250 * 17 + 16];
    proj_body<2, 512>(x, WT, bias, out, Ncols, K, ldx, nullptr, blockIdx.x, xs);
}

// fused scorer projections: blocks [0,256) -> s3 (Ncols=300), [256,512) -> lh
__global__ __launch_bounds__(256)
void proj_s3lh(const float* __restrict__ x,
               const float* __restrict__ WTa, const float* __restrict__ ba,
               float* __restrict__ outa,
               const float* __restrict__ WTb, const float* __restrict__ bb,
               float* __restrict__ outb, const int* __restrict__ gather_idx) {
    __shared__ float xs[250 * 17 + 16];
    int job = blockIdx.x >> 8;
    int blk = blockIdx.x & 255;
    if (job == 0)
        proj_body<2, 256>(x, WTa, ba, outa, 300, H2, H2, nullptr, blk, xs);
    else
        proj_body<2, 256>(x, WTb, bb, outb, 100, H2, H2, gather_idx, blk, xs);
}

// ---------------------------------------------------------------------------
// K3: LSTM scan v12 = v8's L2-streamed weights + v9's single-barrier
// in-register-h structure. v8 (104 us) pays 2 barriers + hbuf round-trip
// per step; v9 proved the 1-barrier redundant-gate form correct (its 142 us
// was isolated to LDS weight contention, removed here). Each wave-pair ks
// computes gates for its OWN k-slice from pbuf (lanes<32), h never touches
// LDS: next step's broadcast reads register pairs via readlane. pbuf is
// double-buffered so the single lgkm-only barrier suffices (v9-proven).
// ---------------------------------------------------------------------------
__global__ __launch_bounds__(512, 2)
void lstm_scan(const float* __restrict__ xgc,
               const unsigned* __restrict__ WhHf, const unsigned* __restrict__ WhHb,
               float* __restrict__ out) {
    __shared__ __align__(16) float pbuf[2][4*512];   // 16 KB
    int dir = blockIdx.x & 1;
    int b = blockIdx.x >> 1;
    const unsigned* WhH = dir ? WhHb : WhHf;   // [64 pk][512 g] u32 f16-pairs
    int off = dir ? D : 0;
    int t = threadIdx.x;
    int lane = t & 63;
    int w = t >> 6;                 // wave 0..7
    int ks = w >> 1;                // k-slice 0..3 (k rows ks*32..+31)
    int cg = ((w & 1) << 6) + lane; // col-group 0..127
    int c0 = cg << 2;               // first gate col 0..508

    const unsigned* wp = WhH + (size_t)(ks*16)*512 + c0;

    const float* xb = xgc + (size_t)b * N * 1000 + dir * 500;
    bool xa = (ks == 0) && (cg < 125);
    float4 zero4 = make_float4(0.f, 0.f, 0.f, 0.f);
    float4 xA = zero4, xB = zero4;          // depth-2 x prefetch
    if (xa) {
        xA = *(const float4*)&xb[(size_t)(dir ? (N-1) : 0)*1000 + c0];
        xB = *(const float4*)&xb[(size_t)(dir ? (N-2) : 1)*1000 + c0];
    }

    int t4 = ks*32 + (lane & 31);           // this lane's gate row
    bool act = (lane < 32) && (t4 < 125);
    bool sto = act && ((w & 1) == 0);       // even wave of pair stores

    unsigned vhp = 0;                       // even lane 2j: f16x2 (h[ks*32+2j], h[+1])
    float c = 0.0f, h = 0.0f;

    for (int ti = 0; ti < N; ti++) {
        int tt = dir ? (N-1-ti) : ti;
        // issue the 16 weight-pair loads early (independent, pipelined, L2)
        uint4 wq[16];
        #pragma unroll
        for (int p = 0; p < 16; p++)
            wq[p] = *(const uint4*)&wp[(size_t)p*512];
        float4 x_cur = xA;
        float4 xC = zero4;
        if (xa && ti + 2 < N) {
            int tn = dir ? (tt-2) : (tt+2);
            xC = *(const float4*)&xb[(size_t)tn*1000 + c0];
        }
        float a0 = x_cur.x, a1 = x_cur.y, a2 = x_cur.z, a3 = x_cur.w;
        #pragma unroll
        for (int p = 0; p < 16; p++) {
            unsigned hp = bcast_lane_u(vhp, 2*p);   // pair at even lane 2p
            a0 = dot2acc(wq[p].x, hp, a0);
            a1 = dot2acc(wq[p].y, hp, a1);
            a2 = dot2acc(wq[p].z, hp, a2);
            a3 = dot2acc(wq[p].w, hp, a3);
        }
        xA = xB; xB = xC;
        float* pb = &pbuf[ti & 1][0];
        *(float4*)&pb[ks*512 + c0] = make_float4(a0, a1, a2, a3);
        // ONE lgkm-only barrier per step (global loads stay in flight)
        asm volatile("s_waitcnt lgkmcnt(0)" ::: "memory");
        __builtin_amdgcn_s_barrier();
        asm volatile("" ::: "memory");
        if (act) {
            float iv = pb[t4]       + pb[512+t4]       + pb[1024+t4]       + pb[1536+t4];
            float fv = pb[125+t4]   + pb[512+125+t4]   + pb[1024+125+t4]   + pb[1536+125+t4];
            float gv = pb[250+t4]   + pb[512+250+t4]   + pb[1024+250+t4]   + pb[1536+250+t4];
            float ov = pb[375+t4]   + pb[512+375+t4]   + pb[1024+375+t4]   + pb[1536+375+t4];
            float si = fast_sigmoid(iv);
            float sf = fast_sigmoid(fv);
            float so = fast_sigmoid(ov);
            c = sf * c + si * fast_tanh(gv);
            h = so * fast_tanh(c);
            if (sto)
                out[(size_t)(b*N + tt)*H2 + off + t4] = h;
        }
        // pack h pairs for next step's broadcast (even lanes valid)
        float hn = __shfl_xor(h, 1);
        vhp = pack_f16x2(h, hn);
    }
}

// ---------------------------------------------------------------------------
// K4a: arc scoring, ITILE=8 (r15-passing: 512 blocks, 1 scheduling round).
// ---------------------------------------------------------------------------
#define ITILE 8
__global__ __launch_bounds__(128)
void arc_score(const float* __restrict__ s3,
               const float* __restrict__ esW, const float* __restrict__ esb,
               const int* __restrict__ ta,
               float* __restrict__ arc_out, float* __restrict__ tree_out) {
    __shared__ float wms[128 * 101];
    __shared__ float whs[ITILE][HID];
    __shared__ float es[HID];
    __shared__ float sv[128];
    __shared__ int   si[128];
    int j = threadIdx.x;
    int blk = blockIdx.x;
    int b = blk >> 4, it = blk & 15;

    // wms: 128 rows x 100 floats from s3 col 100..199 (16B-aligned)
    for (int e = j; e < 128 * 25; e += 128) {
        int r = e / 25, cc = e - r * 25;
        float4 v = *(const float4*)&s3[(size_t)(b*N + r)*300 + 100 + (cc << 2)];
        float* dst = &wms[r*101 + (cc << 2)];
        dst[0] = v.x; dst[1] = v.y; dst[2] = v.z; dst[3] = v.w;
    }
    // whs: ITILE rows x 100 floats from s3 col 0..99
    for (int e = j; e < ITILE * 25; e += 128) {
        int ii = e / 25, cc = e - ii * 25;
        float4 v = *(const float4*)&s3[(size_t)(b*N + it*ITILE + ii)*300 + (cc << 2)];
        float* dst = &whs[ii][cc << 2];
        dst[0] = v.x; dst[1] = v.y; dst[2] = v.z; dst[3] = v.w;
    }
    if (j < HID) es[j] = esW[j];
    __syncthreads();
    float eb = esb[0];
    const float* wmr = &wms[j * 101];
    // ITILE independent acc chains (ILP), h outer
    float acc[ITILE];
    #pragma unroll
    for (int ii = 0; ii < ITILE; ii++) acc[ii] = 0.0f;
    for (int h = 0; h < HID; h++) {
        float wm = wmr[h];
        float ev = es[h];
        #pragma unroll
        for (int ii = 0; ii < ITILE; ii++)
            acc[ii] = fmaf(ev, fast_tanh(whs[ii][h] + wm), acc[ii]);
    }
    for (int ii = 0; ii < ITILE; ii++) {
        int i = it * ITILE + ii;
        int bi = b * N + i;
        int tai = (i == 0) ? 0 : ta[bi];
        float score = acc[ii] + eb + 1.0f - ((j == tai) ? 1.0f : 0.0f);
        arc_out[(size_t)bi*N + j] = score;
        sv[j] = score; si[j] = j;
        __syncthreads();
        for (int s = 64; s; s >>= 1) {
            if (j < s) {
                float ov = sv[j+s]; int oi = si[j+s];
                if (ov > sv[j] || (ov == sv[j] && oi < si[j])) { sv[j] = ov; si[j] = oi; }
            }
            __syncthreads();
        }
        if (j == 0) tree_out[bi] = (float)si[0];
        __syncthreads();
    }
}

// ---------------------------------------------------------------------------
// K4b: rel scoring — own kernel with ~1.5 KB LDS (~16 blocks/CU).
// ---------------------------------------------------------------------------
__global__ __launch_bounds__(128)
void rel_score(const float* __restrict__ s3, const float* __restrict__ rh,
               const float* __restrict__ lsW, const float* __restrict__ lsb,
               float* __restrict__ rel_out, float* __restrict__ pred_out) {
    __shared__ float tv[HID];
    __shared__ float sv[128];
    __shared__ int   si[128];
    int bt = blockIdx.x;
    int j = threadIdx.x;
    if (j < HID)
        tv[j] = fast_tanh(s3[(size_t)bt*300 + 200 + j] + rh[(size_t)bt*HID + j]);
    __syncthreads();
    float score = -1e30f;
    if (j < L) {
        float acc = 0.0f;
        const float* wrow = lsW + j*HID;
        for (int h = 0; h < HID; h++) acc = fmaf(wrow[h], tv[h], acc);
        score = acc + lsb[j];
        rel_out[(size_t)bt*L + j] = score;
    }
    sv[j] = score; si[j] = j;
    __syncthreads();
    for (int s = 64; s; s >>= 1) {
        if (j < s) {
            float ov = sv[j+s]; int oi = si[j+s];
            if (ov > sv[j] || (ov == sv[j] && oi < si[j])) { sv[j] = ov; si[j] = oi; }
        }
        __syncthreads();
    }
    if (j == 0) pred_out[bt] = (float)si[0];
}

// ---------------------------------------------------------------------------
extern "C" void kernel_launch(void* const* d_in, const int* in_sizes, int n_in,
                              void* d_out, int out_size, void* d_ws, size_t ws_size,
                              hipStream_t stream) {
    const int*   word_ids    = (const int*)  d_in[0];
    const int*   upos_ids    = (const int*)  d_in[1];
    const int*   target_arcs = (const int*)  d_in[2];
    const float* wlookup     = (const float*)d_in[3];
    const float* tlookup     = (const float*)d_in[4];
    const float* l0f_Wih = (const float*)d_in[5];
    const float* l0f_Whh = (const float*)d_in[6];
    const float* l0f_b   = (const float*)d_in[7];
    const float* l0b_Wih = (const float*)d_in[8];
    const float* l0b_Whh = (const float*)d_in[9];
    const float* l0b_b   = (const float*)d_in[10];
    const float* l1f_Wih = (const float*)d_in[11];
    const float* l1f_Whh = (const float*)d_in[12];
    const float* l1f_b   = (const float*)d_in[13];
    const float* l1b_Wih = (const float*)d_in[14];
    const float* l1b_Whh = (const float*)d_in[15];
    const float* l1b_b   = (const float*)d_in[16];
    const float* eh_W = (const float*)d_in[17];
    const float* eh_b = (const float*)d_in[18];
    const float* em_W = (const float*)d_in[19];
    const float* em_b = (const float*)d_in[20];
    const float* es_W = (const float*)d_in[21];
    const float* es_b = (const float*)d_in[22];
    const float* lh_W = (const float*)d_in[23];
    const float* lh_b = (const float*)d_in[24];
    const float* lm_W = (const float*)d_in[25];
    const float* lm_b = (const float*)d_in[26];
    const float* ls_W = (const float*)d_in[27];
    const float* ls_b = (const float*)d_in[28];

    float* out = (float*)d_out;
    float* trees_out = out;                         // 4096
    float* preds_out = out + BT;                    // 4096
    float* arc_out   = out + 2*BT;                  // 524288
    float* rel_out   = out + 2*BT + BT*N;           // 204800

    float* ws = (float*)d_ws;
    float* A       = ws;                    // 4,096,000: xg fused [m][1000]; later s3 [m][300]
    float* words   = ws + 4096000;          //   512,000
    float* C       = ws + 4608000;          // 1,024,000: h0, then ex
    float* WT_l0   = ws + 5632000;          //   125,000  [125][1000]
    float* WT_l1   = ws + 5757000;          //   250,000  [250][1000]
    float* WT_s3   = ws + 6007000;          //    75,000  [250][300]
    float* WT_lh   = ws + 6082000;          //    25,000  [250][100]
    unsigned* WhH_l0f = (unsigned*)(ws + 6107000);  // 32,768 u32 [64][512] f16-pairs
    unsigned* WhH_l0b = (unsigned*)(ws + 6139768);  // 32,768
    unsigned* WhH_l1f = (unsigned*)(ws + 6172536);  // 32,768
    unsigned* WhH_l1b = (unsigned*)(ws + 6205304);  // 32,768
    float* b_l0    = ws + 6238072;          //     1,000
    float* b_l1    = ws + 6239072;          //     1,000
    float* b_s3    = ws + 6240072;          //     1,000 (300 used)
    float* rel_head = ws + 6241072;         //   409,600  [m][100]
    // total 6,650,672 floats = 26.6 MB

    // 0. single fused setup launch
    TArgs ta{};
    int n_tr = 0;
    {
        auto tiles = [](int R, int C_) { return ((C_+31)/32) * ((R+31)/32); };
        struct { const float* s; float* d; int R, C, ldo, coff; } js[8] = {
            { l0f_Wih, WT_l0, 500, 125, 1000, 0 },
            { l0b_Wih, WT_l0, 500, 125, 1000, 500 },
            { l1f_Wih, WT_l1, 500, 250, 1000, 0 },
            { l1b_Wih, WT_l1, 500, 250, 1000, 500 },
            { eh_W, WT_s3, 100, 250, 300, 0 },
            { em_W, WT_s3, 100, 250, 300, 100 },
            { lm_W, WT_s3, 100, 250, 300, 200 },
            { lh_W, WT_lh, 100, 250, 100, 0 },
        };
        for (int i = 0; i < 8; i++) {
            ta.j[i].src = js[i].s;  ta.j[i].dst = js[i].d;
            ta.j[i].R = js[i].R;    ta.j[i].C = js[i].C;
            ta.j[i].ldo = js[i].ldo; ta.j[i].coff = js[i].coff;
            ta.j[i].tile0 = n_tr;
            ta.j[i].tiles_x = (js[i].C + 31) / 32;
            n_tr += tiles(js[i].R, js[i].C);
        }
    }
    setup_fused<<<n_tr + 2048 + 9 + 512, 256, 0, stream>>>(
        ta, n_tr, word_ids, upos_ids, wlookup, tlookup, words,
        l0f_b, l0b_b, l1f_b, l1b_b, eh_b, em_b, lm_b,
        b_l0, b_l1, b_s3,
        l0f_Whh, l0b_Whh, l1f_Whh, l1b_Whh,
        WhH_l0f, WhH_l0b, WhH_l1f, WhH_l1b);

    // 1. layer-0 input projections, fused fwd+bwd (K=125, N=1000)
    proj_t<<<BT/MT, 512, 0, stream>>>(words, WT_l0, b_l0, A, 1000, D, D);

    // 2. layer-0 scan -> h0 (C)
    lstm_scan<<<B*2, 512, 0, stream>>>(A, WhH_l0f, WhH_l0b, C);

    // 3. layer-1 input projections (K=250, N=1000)
    proj_t<<<BT/MT, 512, 0, stream>>>(C, WT_l1, b_l1, A, 1000, H2, H2);

    // 4. layer-1 scan -> ex (C, overwrites h0)
    lstm_scan<<<B*2, 512, 0, stream>>>(A, WhH_l1f, WhH_l1b, C);

    // 5. fused scorer projections: s3 (eh+em+lm, N=300) + lh gathered (N=100)
    proj_s3lh<<<512, 256, 0, stream>>>(C, WT_s3, b_s3, A,
                                       WT_lh, lh_b, rel_head, target_arcs);

    // 6. arc scoring/argmax (512 blocks, 1 scheduling round at 2/CU)
    arc_score<<<512, 128, 0, stream>>>(A, es_W, es_b, target_arcs,
                                       arc_out, trees_out);

    // 7. rel scoring/argmax (small-LDS, high occupancy)
    rel_score<<<BT, 128, 0, stream>>>(A, rel_head, ls_W, ls_b,
                                      rel_out, preds_out);
}

// Round 17
// 508.330 us; speedup vs baseline: 1.0841x; 1.0841x over previous
//
#include <hip/hip_runtime.h>
#include <hip/hip_bf16.h>
#include <hip/hip_fp16.h>
#include <math.h>

// Problem constants
#define B 32
#define N 128
#define BT (B*N)          // 4096
#define WD 100
#define UD 25
#define D 125             // LSTM hidden per direction
#define G4 (4*D)          // 500 gates
#define H2 (2*D)          // 250
#define HID 100
#define L 50

// Fast, overflow-safe activations on v_exp_f32
__device__ __forceinline__ float fast_tanh(float x) {
    float e = __expf(2.0f * x);
    return 1.0f - 2.0f / (e + 1.0f);
}
__device__ __forceinline__ float fast_sigmoid(float x) {
    return 1.0f / (1.0f + __expf(-x));
}
__device__ __forceinline__ float bcast_lane(float v, int k) {
    return __builtin_bit_cast(float, __builtin_amdgcn_readlane(__builtin_bit_cast(int, v), k));
}
__device__ __forceinline__ unsigned bcast_lane_u(unsigned v, int k) {
    return (unsigned)__builtin_amdgcn_readlane((int)v, k);
}

// pack two f32 into one u32 of 2 f16 (lo, hi), RTNE
__device__ __forceinline__ unsigned pack_f16x2(float lo, float hi) {
    __half hl = __float2half_rn(lo), hh = __float2half_rn(hi);
    unsigned a = (unsigned)__builtin_bit_cast(unsigned short, hl);
    unsigned b = (unsigned)__builtin_bit_cast(unsigned short, hh);
    return a | (b << 16);
}

typedef _Float16 h2_t __attribute__((ext_vector_type(2)));
// acc += w.lo*h.lo + w.hi*h.hi   (fp32 accumulate)
__device__ __forceinline__ float dot2acc(unsigned wu, unsigned hu, float acc) {
#if __has_builtin(__builtin_amdgcn_fdot2)
    return __builtin_amdgcn_fdot2(__builtin_bit_cast(h2_t, wu),
                                  __builtin_bit_cast(h2_t, hu), acc, false);
#else
    h2_t wv = __builtin_bit_cast(h2_t, wu);
    h2_t hv = __builtin_bit_cast(h2_t, hu);
    acc = fmaf((float)wv[0], (float)hv[0], acc);
    acc = fmaf((float)wv[1], (float)hv[1], acc);
    return acc;
#endif
}

// ---------------------------------------------------------------------------
// K_setup: ONE launch for {8 weight transposes, embedding gather, fused
// biases, Whh f16-pair packing}. Grid: [0,TR) transpose tiles,
// [TR,TR+2048) embed, then 9 bias blocks, then 512 pack blocks.
// ---------------------------------------------------------------------------
struct TJob { const float* src; float* dst; int R, C, ldo, coff, tile0, tiles_x; };
struct TArgs { TJob j[8]; };

__global__ __launch_bounds__(256)
void setup_fused(TArgs a, int n_tr,
                 const int* __restrict__ wids, const int* __restrict__ uids,
                 const float* __restrict__ wl, const float* __restrict__ tl,
                 float* __restrict__ words,
                 const float* __restrict__ l0f_b, const float* __restrict__ l0b_b,
                 const float* __restrict__ l1f_b, const float* __restrict__ l1b_b,
                 const float* __restrict__ eh_b, const float* __restrict__ em_b,
                 const float* __restrict__ lm_b,
                 float* __restrict__ b_l0, float* __restrict__ b_l1,
                 float* __restrict__ b_s3,
                 const float* __restrict__ s0, const float* __restrict__ s1,
                 const float* __restrict__ s2, const float* __restrict__ s3w,
                 unsigned* __restrict__ d0, unsigned* __restrict__ d1,
                 unsigned* __restrict__ d2, unsigned* __restrict__ d3) {
    __shared__ float tile[32][33];
    int bid = blockIdx.x;
    int tid = threadIdx.x;
    if (bid < n_tr) {                    // ---- transpose tiles ----
        int ji = 0;
        #pragma unroll
        for (int i = 1; i < 8; i++) if (bid >= a.j[i].tile0) ji = i;
        TJob jb = a.j[ji];
        int t = bid - jb.tile0;
        int tx = t % jb.tiles_x, ty = t / jb.tiles_x;
        int txx = tid & 31, tyy = tid >> 5;      // 32 x 8
        int k0 = tx*32, n0 = ty*32;
        #pragma unroll
        for (int dy = 0; dy < 32; dy += 8) {
            int n = n0 + tyy + dy, k = k0 + txx;
            if (n < jb.R && k < jb.C)
                tile[tyy+dy][txx] = jb.src[(size_t)n*jb.C + k];
        }
        __syncthreads();
        #pragma unroll
        for (int dy = 0; dy < 32; dy += 8) {
            int k = k0 + tyy + dy, n = n0 + txx;
            if (k < jb.C && n < jb.R)
                jb.dst[(size_t)k*jb.ldo + jb.coff + n] = tile[txx][tyy+dy];
        }
        return;
    }
    bid -= n_tr;
    if (bid < 2048) {                    // ---- embed: 2 bt per block ----
        int bt = bid*2 + (tid >> 7);
        int t = tid & 127;
        int wid = wids[bt], uid = uids[bt];
        if (t < WD)       words[bt*D + t] = wl[(size_t)wid*WD + t];
        else if (t < D)   words[bt*D + t] = tl[(size_t)uid*UD + (t - WD)];
        return;
    }
    bid -= 2048;
    if (bid < 9) {                       // ---- fused biases ----
        int t = bid*256 + tid;
        if (t < 500)        b_l0[t] = l0f_b[t];
        else if (t < 1000)  b_l0[t] = l0b_b[t-500];
        else if (t < 1500)  b_l1[t-1000] = l1f_b[t-1000];
        else if (t < 2000)  b_l1[t-1000] = l1b_b[t-1500];
        else if (t < 2100)  b_s3[t-2000] = eh_b[t-2000];
        else if (t < 2200)  b_s3[t-2000] = em_b[t-2100];
        else if (t < 2300)  b_s3[t-2000] = lm_b[t-2200];
        return;
    }
    bid -= 9;                            // ---- Whh f16-pair pack (512 blocks) ----
    // WhH[pk][g] (u32, [64][512]) = pack_f16x2(Whh[g][2pk], Whh[g][2pk+1])
    // Whh is [500][125] row-major; zero-fill k>=125, g>=500.
    int e = bid*256 + tid;               // exactly 4*64*512 = 131072
    int m = e >> 15;                     // buffer 0..3
    int r = e & 32767;
    int pk = r >> 9;                     // 0..63
    int g  = r & 511;                    // 0..511
    const float* s = (m == 0) ? s0 : (m == 1) ? s1 : (m == 2) ? s2 : s3w;
    unsigned* dd   = (m == 0) ? d0 : (m == 1) ? d1 : (m == 2) ? d2 : d3;
    float v0 = 0.0f, v1 = 0.0f;
    if (g < 500) {
        int k0 = pk << 1;
        if (k0 < 125)     v0 = s[(size_t)g*125 + k0];
        if (k0 + 1 < 125) v1 = s[(size_t)g*125 + k0 + 1];
    }
    dd[(pk << 9) + g] = pack_f16x2(v0, v1);
}

// ---------------------------------------------------------------------------
// K2: projection GEMM, transposed weights, CPT columns per thread,
//     software-pipelined WT loads (prefetch next k-group).
// ---------------------------------------------------------------------------
#define MT 16
template<int CPT, int BD>
__device__ __forceinline__
void proj_body(const float* __restrict__ x, const float* __restrict__ WT,
               const float* __restrict__ bias, float* __restrict__ out,
               int Ncols, int K, int ldx, const int* __restrict__ gather_idx,
               int blk, float* xs) {
    int m0 = blk * MT;
    for (int e = threadIdx.x; e < MT * K; e += BD) {
        int r = e / K, k = e - r * K;
        int m = m0 + r;
        int row = m;
        if (gather_idx) {
            int bb = m >> 7, np = m & 127;
            row = (bb << 7) + (np == 0 ? 0 : gather_idx[m]);
        }
        xs[k*17 + r] = x[(size_t)row*ldx + k];
    }
    __syncthreads();
    int n0 = threadIdx.x;
    int lane = threadIdx.x & 63;
    float acc[CPT][MT];
    int ncl[CPT];
    #pragma unroll
    for (int j = 0; j < CPT; j++) {
        int n = n0 + j*BD;
        ncl[j] = (n < Ncols) ? n : (Ncols - 1);
        #pragma unroll
        for (int r = 0; r < MT; r++) acc[j][r] = 0.0f;
    }
    float wkc[4][CPT];
    #pragma unroll
    for (int q = 0; q < 4; q++)
        #pragma unroll
        for (int j = 0; j < CPT; j++)
            wkc[q][j] = WT[(size_t)q*Ncols + ncl[j]];
    int k0 = 0;
    for (; k0 + 8 <= K; k0 += 4) {
        float xv = xs[(k0 + (lane >> 4))*17 + (lane & 15)];
        float wkn[4][CPT];
        #pragma unroll
        for (int q = 0; q < 4; q++)
            #pragma unroll
            for (int j = 0; j < CPT; j++)
                wkn[q][j] = WT[(size_t)(k0 + 4 + q)*Ncols + ncl[j]];
        #pragma unroll
        for (int q = 0; q < 4; q++) {
            #pragma unroll
            for (int r = 0; r < 16; r++) {
                float hv = bcast_lane(xv, q*16 + r);
                #pragma unroll
                for (int j = 0; j < CPT; j++)
                    acc[j][r] = fmaf(wkc[q][j], hv, acc[j][r]);
            }
        }
        #pragma unroll
        for (int q = 0; q < 4; q++)
            #pragma unroll
            for (int j = 0; j < CPT; j++)
                wkc[q][j] = wkn[q][j];
    }
    { // last full group
        float xv = xs[(k0 + (lane >> 4))*17 + (lane & 15)];
        #pragma unroll
        for (int q = 0; q < 4; q++) {
            #pragma unroll
            for (int r = 0; r < 16; r++) {
                float hv = bcast_lane(xv, q*16 + r);
                #pragma unroll
                for (int j = 0; j < CPT; j++)
                    acc[j][r] = fmaf(wkc[q][j], hv, acc[j][r]);
            }
        }
        k0 += 4;
    }
    for (; k0 < K; k0++) {
        float xv = xs[k0*17 + (lane & 15)];
        float wk[CPT];
        #pragma unroll
        for (int j = 0; j < CPT; j++) wk[j] = WT[(size_t)k0*Ncols + ncl[j]];
        #pragma unroll
        for (int r = 0; r < 16; r++) {
            float hv = bcast_lane(xv, r);
            #pragma unroll
            for (int j = 0; j < CPT; j++)
                acc[j][r] = fmaf(wk[j], hv, acc[j][r]);
        }
    }
    #pragma unroll
    for (int j = 0; j < CPT; j++) {
        int n = n0 + j*BD;
        if (n < Ncols) {
            float bb = bias[n];
            #pragma unroll
            for (int r = 0; r < MT; r++) out[(size_t)(m0 + r)*Ncols + n] = acc[j][r] + bb;
        }
    }
}

__global__ __launch_bounds__(512)
void proj_t(const float* __restrict__ x, const float* __restrict__ WT,
            const float* __restrict__ bias, float* __restrict__ out,
            int Ncols, int K, int ldx) {
    __shared__ float xs[250 * 17 + 16];
    proj_body<2, 512>(x, WT, bias, out, Ncols, K, ldx, nullptr, blockIdx.x, xs);
}

// fused scorer projections: blocks [0,256) -> s3 (Ncols=300), [256,512) -> lh
__global__ __launch_bounds__(256)
void proj_s3lh(const float* __restrict__ x,
               const float* __restrict__ WTa, const float* __restrict__ ba,
               float* __restrict__ outa,
               const float* __restrict__ WTb, const float* __restrict__ bb,
               float* __restrict__ outb, const int* __restrict__ gather_idx) {
    __shared__ float xs[250 * 17 + 16];
    int job = blockIdx.x >> 8;
    int blk = blockIdx.x & 255;
    if (job == 0)
        proj_body<2, 256>(x, WTa, ba, outa, 300, H2, H2, nullptr, blk, xs);
    else
        proj_body<2, 256>(x, WTb, bb, outb, 100, H2, H2, gather_idx, blk, xs);
}

// ---------------------------------------------------------------------------
// K3: LSTM scan — v8 verbatim (champion, 104 us). Final post-mortem: the
// register path (v3-v6), LDS path (v7/v9), AGPR path (v11), dual-pipe
// (v10), and single-barrier hybrid (v12, +23 us) all lose to this form.
// The ~1950 cyc/step is L2-latency exposure the source level cannot
// remove; the 2-barrier + hbuf structure is the measured local optimum.
// ---------------------------------------------------------------------------
__global__ __launch_bounds__(512, 2)
void lstm_scan(const float* __restrict__ xgc,
               const unsigned* __restrict__ WhHf, const unsigned* __restrict__ WhHb,
               float* __restrict__ out) {
    int dir = blockIdx.x & 1;
    int b = blockIdx.x >> 1;
    const unsigned* WhH = dir ? WhHb : WhHf;   // [64 pk][512 g] u32 f16-pairs
    int off = dir ? D : 0;
    int t = threadIdx.x;
    int lane = t & 63;
    int w = t >> 6;                 // wave 0..7
    int ks = w >> 1;                // k-slice 0..3 (k rows ks*32..+31)
    int cg = ((w & 1) << 6) + lane; // col-group 0..127
    int c0 = cg << 2;               // first gate col 0..508

    __shared__ __align__(16) float hbuf[128];
    __shared__ __align__(16) float pbuf[4*512];

    const unsigned* wp = WhH + (size_t)(ks*16)*512 + c0;

    const float* xb = xgc + (size_t)b * N * 1000 + dir * 500;
    bool xa = (ks == 0) && (cg < 125);
    float4 zero4 = make_float4(0.f, 0.f, 0.f, 0.f);
    float4 xA = zero4, xB = zero4;          // depth-2 x prefetch
    if (xa) {
        xA = *(const float4*)&xb[(size_t)(dir ? (N-1) : 0)*1000 + c0];
        xB = *(const float4*)&xb[(size_t)(dir ? (N-2) : 1)*1000 + c0];
    }

    if (t < 128) hbuf[t] = 0.0f;
    __syncthreads();

    float c = 0.0f;
    for (int ti = 0; ti < N; ti++) {
        int tt = dir ? (N-1-ti) : ti;
        // issue the 16 weight-pair loads early (independent, pipelined)
        uint4 wq[16];
        #pragma unroll
        for (int p = 0; p < 16; p++)
            wq[p] = *(const uint4*)&wp[(size_t)p*512];
        // h pair pack: lanes 0-15 hold (h[ks*32+2j], h[ks*32+2j+1])
        float2 h2 = *(const float2*)&hbuf[ks*32 + ((lane & 15) << 1)];
        unsigned vhp = pack_f16x2(h2.x, h2.y);
        float4 x_cur = xA;
        float4 xC = zero4;
        if (xa && ti + 2 < N) {
            int tn = dir ? (tt-2) : (tt+2);
            xC = *(const float4*)&xb[(size_t)tn*1000 + c0];
        }
        float a0 = x_cur.x, a1 = x_cur.y, a2 = x_cur.z, a3 = x_cur.w;
        #pragma unroll
        for (int p = 0; p < 16; p++) {
            unsigned hp = bcast_lane_u(vhp, p);
            a0 = dot2acc(wq[p].x, hp, a0);
            a1 = dot2acc(wq[p].y, hp, a1);
            a2 = dot2acc(wq[p].z, hp, a2);
            a3 = dot2acc(wq[p].w, hp, a3);
        }
        xA = xB; xB = xC;
        *(float4*)&pbuf[ks*512 + c0] = make_float4(a0, a1, a2, a3);
        // lgkm-only barrier: weight/x global loads never vmcnt-drained
        asm volatile("s_waitcnt lgkmcnt(0)" ::: "memory");
        __builtin_amdgcn_s_barrier();
        asm volatile("" ::: "memory");
        if (t < D) {
            float iv = pbuf[t]       + pbuf[512+t]       + pbuf[1024+t]       + pbuf[1536+t];
            float fv = pbuf[125+t]   + pbuf[512+125+t]   + pbuf[1024+125+t]   + pbuf[1536+125+t];
            float gv = pbuf[250+t]   + pbuf[512+250+t]   + pbuf[1024+250+t]   + pbuf[1536+250+t];
            float ov = pbuf[375+t]   + pbuf[512+375+t]   + pbuf[1024+375+t]   + pbuf[1536+375+t];
            float si = fast_sigmoid(iv);
            float sf = fast_sigmoid(fv);
            float so = fast_sigmoid(ov);
            c = sf * c + si * fast_tanh(gv);
            float h = so * fast_tanh(c);
            hbuf[t] = h;
            out[(size_t)(b*N + tt)*H2 + off + t] = h;
        }
        asm volatile("s_waitcnt lgkmcnt(0)" ::: "memory");
        __builtin_amdgcn_s_barrier();
        asm volatile("" ::: "memory");
    }
}

// ---------------------------------------------------------------------------
// K4a: arc scoring, ITILE=8 (r15-passing: 512 blocks, 1 scheduling round).
// ---------------------------------------------------------------------------
#define ITILE 8
__global__ __launch_bounds__(128)
void arc_score(const float* __restrict__ s3,
               const float* __restrict__ esW, const float* __restrict__ esb,
               const int* __restrict__ ta,
               float* __restrict__ arc_out, float* __restrict__ tree_out) {
    __shared__ float wms[128 * 101];
    __shared__ float whs[ITILE][HID];
    __shared__ float es[HID];
    __shared__ float sv[128];
    __shared__ int   si[128];
    int j = threadIdx.x;
    int blk = blockIdx.x;
    int b = blk >> 4, it = blk & 15;

    // wms: 128 rows x 100 floats from s3 col 100..199 (16B-aligned)
    for (int e = j; e < 128 * 25; e += 128) {
        int r = e / 25, cc = e - r * 25;
        float4 v = *(const float4*)&s3[(size_t)(b*N + r)*300 + 100 + (cc << 2)];
        float* dst = &wms[r*101 + (cc << 2)];
        dst[0] = v.x; dst[1] = v.y; dst[2] = v.z; dst[3] = v.w;
    }
    // whs: ITILE rows x 100 floats from s3 col 0..99
    for (int e = j; e < ITILE * 25; e += 128) {
        int ii = e / 25, cc = e - ii * 25;
        float4 v = *(const float4*)&s3[(size_t)(b*N + it*ITILE + ii)*300 + (cc << 2)];
        float* dst = &whs[ii][cc << 2];
        dst[0] = v.x; dst[1] = v.y; dst[2] = v.z; dst[3] = v.w;
    }
    if (j < HID) es[j] = esW[j];
    __syncthreads();
    float eb = esb[0];
    const float* wmr = &wms[j * 101];
    // ITILE independent acc chains (ILP), h outer
    float acc[ITILE];
    #pragma unroll
    for (int ii = 0; ii < ITILE; ii++) acc[ii] = 0.0f;
    for (int h = 0; h < HID; h++) {
        float wm = wmr[h];
        float ev = es[h];
        #pragma unroll
        for (int ii = 0; ii < ITILE; ii++)
            acc[ii] = fmaf(ev, fast_tanh(whs[ii][h] + wm), acc[ii]);
    }
    for (int ii = 0; ii < ITILE; ii++) {
        int i = it * ITILE + ii;
        int bi = b * N + i;
        int tai = (i == 0) ? 0 : ta[bi];
        float score = acc[ii] + eb + 1.0f - ((j == tai) ? 1.0f : 0.0f);
        arc_out[(size_t)bi*N + j] = score;
        sv[j] = score; si[j] = j;
        __syncthreads();
        for (int s = 64; s; s >>= 1) {
            if (j < s) {
                float ov = sv[j+s]; int oi = si[j+s];
                if (ov > sv[j] || (ov == sv[j] && oi < si[j])) { sv[j] = ov; si[j] = oi; }
            }
            __syncthreads();
        }
        if (j == 0) tree_out[bi] = (float)si[0];
        __syncthreads();
    }
}

// ---------------------------------------------------------------------------
// K4b: rel scoring — own kernel with ~1.5 KB LDS (~16 blocks/CU).
// ---------------------------------------------------------------------------
__global__ __launch_bounds__(128)
void rel_score(const float* __restrict__ s3, const float* __restrict__ rh,
               const float* __restrict__ lsW, const float* __restrict__ lsb,
               float* __restrict__ rel_out, float* __restrict__ pred_out) {
    __shared__ float tv[HID];
    __shared__ float sv[128];
    __shared__ int   si[128];
    int bt = blockIdx.x;
    int j = threadIdx.x;
    if (j < HID)
        tv[j] = fast_tanh(s3[(size_t)bt*300 + 200 + j] + rh[(size_t)bt*HID + j]);
    __syncthreads();
    float score = -1e30f;
    if (j < L) {
        float acc = 0.0f;
        const float* wrow = lsW + j*HID;
        for (int h = 0; h < HID; h++) acc = fmaf(wrow[h], tv[h], acc);
        score = acc + lsb[j];
        rel_out[(size_t)bt*L + j] = score;
    }
    sv[j] = score; si[j] = j;
    __syncthreads();
    for (int s = 64; s; s >>= 1) {
        if (j < s) {
            float ov = sv[j+s]; int oi = si[j+s];
            if (ov > sv[j] || (ov == sv[j] && oi < si[j])) { sv[j] = ov; si[j] = oi; }
        }
        __syncthreads();
    }
    if (j == 0) pred_out[bt] = (float)si[0];
}

// ---------------------------------------------------------------------------
extern "C" void kernel_launch(void* const* d_in, const int* in_sizes, int n_in,
                              void* d_out, int out_size, void* d_ws, size_t ws_size,
                              hipStream_t stream) {
    const int*   word_ids    = (const int*)  d_in[0];
    const int*   upos_ids    = (const int*)  d_in[1];
    const int*   target_arcs = (const int*)  d_in[2];
    const float* wlookup     = (const float*)d_in[3];
    const float* tlookup     = (const float*)d_in[4];
    const float* l0f_Wih = (const float*)d_in[5];
    const float* l0f_Whh = (const float*)d_in[6];
    const float* l0f_b   = (const float*)d_in[7];
    const float* l0b_Wih = (const float*)d_in[8];
    const float* l0b_Whh = (const float*)d_in[9];
    const float* l0b_b   = (const float*)d_in[10];
    const float* l1f_Wih = (const float*)d_in[11];
    const float* l1f_Whh = (const float*)d_in[12];
    const float* l1f_b   = (const float*)d_in[13];
    const float* l1b_Wih = (const float*)d_in[14];
    const float* l1b_Whh = (const float*)d_in[15];
    const float* l1b_b   = (const float*)d_in[16];
    const float* eh_W = (const float*)d_in[17];
    const float* eh_b = (const float*)d_in[18];
    const float* em_W = (const float*)d_in[19];
    const float* em_b = (const float*)d_in[20];
    const float* es_W = (const float*)d_in[21];
    const float* es_b = (const float*)d_in[22];
    const float* lh_W = (const float*)d_in[23];
    const float* lh_b = (const float*)d_in[24];
    const float* lm_W = (const float*)d_in[25];
    const float* lm_b = (const float*)d_in[26];
    const float* ls_W = (const float*)d_in[27];
    const float* ls_b = (const float*)d_in[28];

    float* out = (float*)d_out;
    float* trees_out = out;                         // 4096
    float* preds_out = out + BT;                    // 4096
    float* arc_out   = out + 2*BT;                  // 524288
    float* rel_out   = out + 2*BT + BT*N;           // 204800

    float* ws = (float*)d_ws;
    float* A       = ws;                    // 4,096,000: xg fused [m][1000]; later s3 [m][300]
    float* words   = ws + 4096000;          //   512,000
    float* C       = ws + 4608000;          // 1,024,000: h0, then ex
    float* WT_l0   = ws + 5632000;          //   125,000  [125][1000]
    float* WT_l1   = ws + 5757000;          //   250,000  [250][1000]
    float* WT_s3   = ws + 6007000;          //    75,000  [250][300]
    float* WT_lh   = ws + 6082000;          //    25,000  [250][100]
    unsigned* WhH_l0f = (unsigned*)(ws + 6107000);  // 32,768 u32 [64][512] f16-pairs
    unsigned* WhH_l0b = (unsigned*)(ws + 6139768);  // 32,768
    unsigned* WhH_l1f = (unsigned*)(ws + 6172536);  // 32,768
    unsigned* WhH_l1b = (unsigned*)(ws + 6205304);  // 32,768
    float* b_l0    = ws + 6238072;          //     1,000
    float* b_l1    = ws + 6239072;          //     1,000
    float* b_s3    = ws + 6240072;          //     1,000 (300 used)
    float* rel_head = ws + 6241072;         //   409,600  [m][100]
    // total 6,650,672 floats = 26.6 MB

    // 0. single fused setup launch
    TArgs ta{};
    int n_tr = 0;
    {
        auto tiles = [](int R, int C_) { return ((C_+31)/32) * ((R+31)/32); };
        struct { const float* s; float* d; int R, C, ldo, coff; } js[8] = {
            { l0f_Wih, WT_l0, 500, 125, 1000, 0 },
            { l0b_Wih, WT_l0, 500, 125, 1000, 500 },
            { l1f_Wih, WT_l1, 500, 250, 1000, 0 },
            { l1b_Wih, WT_l1, 500, 250, 1000, 500 },
            { eh_W, WT_s3, 100, 250, 300, 0 },
            { em_W, WT_s3, 100, 250, 300, 100 },
            { lm_W, WT_s3, 100, 250, 300, 200 },
            { lh_W, WT_lh, 100, 250, 100, 0 },
        };
        for (int i = 0; i < 8; i++) {
            ta.j[i].src = js[i].s;  ta.j[i].dst = js[i].d;
            ta.j[i].R = js[i].R;    ta.j[i].C = js[i].C;
            ta.j[i].ldo = js[i].ldo; ta.j[i].coff = js[i].coff;
            ta.j[i].tile0 = n_tr;
            ta.j[i].tiles_x = (js[i].C + 31) / 32;
            n_tr += tiles(js[i].R, js[i].C);
        }
    }
    setup_fused<<<n_tr + 2048 + 9 + 512, 256, 0, stream>>>(
        ta, n_tr, word_ids, upos_ids, wlookup, tlookup, words,
        l0f_b, l0b_b, l1f_b, l1b_b, eh_b, em_b, lm_b,
        b_l0, b_l1, b_s3,
        l0f_Whh, l0b_Whh, l1f_Whh, l1b_Whh,
        WhH_l0f, WhH_l0b, WhH_l1f, WhH_l1b);

    // 1. layer-0 input projections, fused fwd+bwd (K=125, N=1000)
    proj_t<<<BT/MT, 512, 0, stream>>>(words, WT_l0, b_l0, A, 1000, D, D);

    // 2. layer-0 scan -> h0 (C)
    lstm_scan<<<B*2, 512, 0, stream>>>(A, WhH_l0f, WhH_l0b, C);

    // 3. layer-1 input projections (K=250, N=1000)
    proj_t<<<BT/MT, 512, 0, stream>>>(C, WT_l1, b_l1, A, 1000, H2, H2);

    // 4. layer-1 scan -> ex (C, overwrites h0)
    lstm_scan<<<B*2, 512, 0, stream>>>(A, WhH_l1f, WhH_l1b, C);

    // 5. fused scorer projections: s3 (eh+em+lm, N=300) + lh gathered (N=100)
    proj_s3lh<<<512, 256, 0, stream>>>(C, WT_s3, b_s3, A,
                                       WT_lh, lh_b, rel_head, target_arcs);

    // 6. arc scoring/argmax (512 blocks, 1 scheduling round at 2/CU)
    arc_score<<<512, 128, 0, stream>>>(A, es_W, es_b, target_arcs,
                                       arc_out, trees_out);

    // 7. rel scoring/argmax (small-LDS, high occupancy)
    rel_score<<<BT, 128, 0, stream>>>(A, rel_head, ls_W, ls_b,
                                      rel_out, preds_out);
}